// Round 8
// baseline (104.162 us; speedup 1.0000x reference)
//
#include <hip/hip_runtime.h>
#include <hip/hip_fp16.h>
#include <math.h>

#define P      512
#define NA     180
#define NB     4
#define FOFFH  64               // leading zero-pad HALVES per angle row (16 positions x 4 batches)
#define FSH    (FOFFH + 4 * P + FOFFH)   // 2176 halves: pad + 4-batch-interleaved fp16 data + pad
#define GUARD  512              // float guard before fil2h for window-staging underreach
#define TS     16               // backprojection pixel tile 16x16 (1024 blocks)
#define WPOS   28               // window positions per angle
#define WCHK   (WPOS / 2)       // 14 x 16B staging chunks per angle (2 positions each)
#define WU32   (WPOS * 2)       // 56 u32 per angle slot (28 positions x 4 batches x fp16)
#define ASEG   60               // angles staged per LDS round (3 segments)
#define NTILES (32 * 32)

#if __has_builtin(__builtin_amdgcn_fractf)
#define FRACT(x) __builtin_amdgcn_fractf(x)
#else
#define FRACT(x) ((x) - floorf(x))
#endif

typedef float f4 __attribute__((ext_vector_type(4), aligned(16)));
typedef _Float16 h4 __attribute__((ext_vector_type(4), aligned(8)));
typedef unsigned int u32;

static __device__ __forceinline__ float2 h2f2(u32 v) {   // 2 packed halves -> 2 floats
    __half2 h = *reinterpret_cast<__half2*>(&v);
    return __half22float2(h);
}

// ===========================================================================
// Compile-time tables (unchanged from r3): hr (Shepp-Logan ramp impulse
// response) and the angle sin/cos table are input-independent constexpr
// __constant__ data. f64 Taylor sin/cos (quarter-wave reduced) ~1 ulp.
// ===========================================================================
constexpr double PI_D = 3.14159265358979323846264338327950288;

struct D512 { double v[512]; };
struct F512 { float v[512]; };
struct SCT2 { float sc[NA][2]; };

constexpr double cosap(double x) {   // |x| <= ~pi/2, Taylor to x^24
    double invf[13] = {};
    double f = 1.0; invf[0] = 1.0;
    for (int n = 1; n <= 12; ++n) { f *= (double)((2 * n - 1) * (2 * n)); invf[n] = 1.0 / f; }
    const double x2 = x * x;
    double r = invf[12];
    for (int n = 11; n >= 0; --n) r = invf[n] - x2 * r;
    return r;
}
constexpr double sinap(double x) {   // |x| <= ~pi/2, Taylor to x^25
    double invf[13] = {};
    double f = 1.0; invf[0] = 1.0;
    for (int n = 1; n <= 12; ++n) { f *= (double)((2 * n) * (2 * n + 1)); invf[n] = 1.0 / f; }
    const double x2 = x * x;
    double r = invf[12];
    for (int n = 11; n >= 0; --n) r = invf[n] - x2 * r;
    return x * r;
}

constexpr D512 make_ct() {           // cos(2*pi*ph/512), quarter-wave reduced
    D512 t{};
    for (int ph = 0; ph < 512; ++ph) {
        const int q = ph >> 7, r = ph & 127;
        double v = 0.0;
        if (q == 0)      v =  cosap(PI_D * (double)r / 256.0);
        else if (q == 1) v = -cosap(PI_D * (double)(128 - r) / 256.0);
        else if (q == 2) v = -cosap(PI_D * (double)r / 256.0);
        else             v =  cosap(PI_D * (double)(128 - r) / 256.0);
        t.v[ph] = v;
    }
    return t;
}
constexpr D512 CT = make_ct();

constexpr F512 make_ffg() {
    F512 t{};
    double fv[128] = {};
    for (int mm = 0; mm < 128; ++mm) {
        const double pn = PI_D * (double)(2 * mm + 1);
        fv[mm] = -1.0 / (pn * pn);
    }
    for (int o = 0; o <= 256; ++o) {
        double s = 0.0;
        for (int mm = 0; mm < 128; ++mm)
            s += fv[mm] * CT.v[(o * (2 * mm + 1)) & 511];
        double ff = 0.5 + 4.0 * s;           // 0.5 + 2*(2*s_half)
        if (o > 0) {
            const double w = PI_D * (double)o / 512.0;
            ff *= sinap(w) / w;
        }
        t.v[o] = (float)ff;
    }
    for (int o = 257; o < 512; ++o) t.v[o] = t.v[512 - o];
    return t;
}
constexpr F512 FFG = make_ffg();

constexpr F512 make_hr_part(int lo, int hi) {
    F512 t{};
    for (int o = lo; o < hi; ++o) {
        double s2 = 0.0;
        for (int k = 1; k < 256; ++k)
            s2 += (double)FFG.v[k] * CT.v[(o * k) & 511];
        double s = (double)FFG.v[0] + (double)FFG.v[256] * CT.v[(o * 256) & 511] + 2.0 * s2;
        t.v[o] = (float)(s / 512.0);
    }
    return t;
}
constexpr F512 HR_A = make_hr_part(0, 129);
constexpr F512 HR_B = make_hr_part(129, 257);

constexpr F512 make_hr() {
    F512 t{};
    for (int o = 0; o < 129; ++o)   t.v[o] = HR_A.v[o];
    for (int o = 129; o < 257; ++o) t.v[o] = HR_B.v[o];
    for (int o = 257; o < 512; ++o) t.v[o] = t.v[512 - o];
    return t;
}
__constant__ F512 HRC = make_hr();

constexpr SCT2 make_sct() {
    SCT2 t{};
    for (int a = 0; a < NA; ++a) {
        const float thf = (float)a * (float)(PI_D / 179.0);
        const double x = (double)thf;        // in [0, ~pi]
        double sv, cv;
        if (x <= PI_D * 0.5) { sv = sinap(x);        cv =  cosap(x); }
        else                 { sv = sinap(PI_D - x); cv = -cosap(PI_D - x); }
        t.sc[a][0] = (float)sv;
        t.sc[a][1] = (float)cv;
    }
    return t;
}
__constant__ SCT2 SCT = make_sct();

// ---------------------------------------------------------------------------
// K2 (identical to r7, which passed): one 512-thread block per angle:
// circular conv for ALL 4 batches, f32 rolling-register-window chain
// bit-identical to r3. Output FP16 4-batch interleaved (half index
// FOFFH + 4*pos + b), rounded once at store. qbt build fused in the tail.
// ---------------------------------------------------------------------------
__global__ __launch_bounds__(512) void ir_filter(const float* __restrict__ sino,
                                                 _Float16* __restrict__ fil2h,
                                                 float* __restrict__ qbt) {
    __shared__ __align__(16) float row2[4][2 * P];
    __shared__ __align__(16) float sOut[4 * P];
    const int a = blockIdx.x;
    const int t = threadIdx.x;

    const int b = t >> 7;             // batch 0..3
    const int tt = t & 127;           // outputs 4tt..4tt+3

    const float* src = sino + ((size_t)b * NA + a) * P;
    const float4 v = *(const float4*)(src + 4 * tt);
    *(float4*)&row2[b][4 * tt] = v;
    *(float4*)&row2[b][4 * tt + P] = v;
    __syncthreads();

    const int base0 = P + 4 * tt;
    float4 A = *(const float4*)&row2[b][base0];    // window floats w[0..3]
    float a0 = 0.f, a1 = 0.f, a2 = 0.f, a3 = 0.f;
    #pragma unroll 4
    for (int J = 0; J < P; J += 4) {
        const float4 Bv = *(const float4*)&row2[b][base0 - J - 4];  // w[-4..-1]
        const float h0 = HRC.v[J], h1 = HRC.v[J + 1], h2v = HRC.v[J + 2], h3 = HRC.v[J + 3];
        a0 = fmaf(h0, A.x, a0); a0 = fmaf(h1, Bv.w, a0); a0 = fmaf(h2v, Bv.z, a0); a0 = fmaf(h3, Bv.y, a0);
        a1 = fmaf(h0, A.y, a1); a1 = fmaf(h1, A.x, a1); a1 = fmaf(h2v, Bv.w, a1); a1 = fmaf(h3, Bv.z, a1);
        a2 = fmaf(h0, A.z, a2); a2 = fmaf(h1, A.y, a2); a2 = fmaf(h2v, A.x, a2); a2 = fmaf(h3, Bv.w, a2);
        a3 = fmaf(h0, A.w, a3); a3 = fmaf(h1, A.z, a3); a3 = fmaf(h2v, A.y, a3); a3 = fmaf(h3, A.x, a3);
        A = Bv;                                    // slide the register window
    }
    // interleave via LDS: half index in data region = 4*pos + b, pos = 4tt+d
    const int o0 = 16 * tt + b;
    sOut[o0]      = a0;
    sOut[o0 + 4]  = a1;
    sOut[o0 + 8]  = a2;
    sOut[o0 + 12] = a3;
    __syncthreads();

    _Float16* frowh = fil2h + (size_t)a * FSH;
    const float4 sv = *(const float4*)(sOut + 4 * t);
    h4 hv;
    hv.x = (_Float16)sv.x; hv.y = (_Float16)sv.y;
    hv.z = (_Float16)sv.z; hv.w = (_Float16)sv.w;
    *(h4*)(frowh + FOFFH + 4 * t) = hv;            // 8B coalesced
    if (t < FOFFH) {                  // zero pads (ws re-poisoned every call)
        frowh[t] = (_Float16)0.f;
        frowh[FOFFH + 4 * P + t] = (_Float16)0.f;
    }

    // fused window-base table for this angle (unchanged)
    const float sa = SCT.sc[a][0];
    const float ca = SCT.sc[a][1];
    #pragma unroll
    for (int i = 0; i < 2; ++i) {
        const int tile = t + 512 * i;          // by*32+bx
        const int bx = tile & 31, by = tile >> 5;
        const float xlo = (float)(240 - 16 * bx);   // min x over tile
        const float ylo = (float)(16 * by - 256);
        const float yhi = (float)(16 * by - 241);
        const float pmin = fmaf(sa, xlo, fminf(ca * ylo, ca * yhi) + 256.0f);
        const int base = ((int)floorf(pmin) - 2) & ~1;  // even, fp-slop safety
        qbt[tile * NA + a] = (float)(256 - base);
    }
}

// ---------------------------------------------------------------------------
// K3: backprojection, r3's proven structure (256 thr, 1024 blocks, 16
// waves/CU) with FP16 windows held in INTEGER-TYPED LDS. All LDS accesses
// are u32-vector typed (uint4 staging, uint2 tap pairs) so the compiler
// cannot scalarize into ds_read_u16 (r7's suspected failure). Both bilinear
// taps x 4 batches = 16B -> two adjacent 8B reads (mergeable to
// ds_read2_b64), halving the DS-pipe cost r3 saturated. Conversion via
// packed-half v_cvt (2 floats/inst); f32 accumulate; tap values, fma order
// and output are BIT-IDENTICAL to r7's passed run.
// ---------------------------------------------------------------------------
__global__ __launch_bounds__(256) void ir_backproject(const _Float16* __restrict__ fil2h,
                                                      const float* __restrict__ qbt,
                                                      float* __restrict__ out) {
    __shared__ __align__(16) u32 win32[ASEG * WU32 + 8];   // 13.4 KB + slack

    const int t = threadIdx.x;
    const int w0 = blockIdx.x * TS, h0 = blockIdx.y * TS;
    const float* qrow = qbt + (blockIdx.y * 32 + blockIdx.x) * NA;  // tile bases

    const int w = w0 + (t & 15);
    const int h = h0 + (t >> 4);

    const int ix = 255 - w;              // reversed x axis
    const int iy = h - 256;
    const int m = (ix * ix + iy * iy) <= 256 * 256;

    float* o0 = out + (size_t)h * P + w;

    if (__syncthreads_count(m) == 0) {   // tile fully outside circle
        o0[0] = 0.f;
        o0[(size_t)P * P] = 0.f;
        o0[(size_t)2 * P * P] = 0.f;
        o0[(size_t)3 * P * P] = 0.f;
        return;
    }

    const float xf = (float)ix;
    const float yf = (float)iy;
    float acc0 = 0.f, acc1 = 0.f, acc2 = 0.f, acc3 = 0.f;

    #pragma unroll
    for (int seg = 0; seg < 3; ++seg) {
        const int A0 = seg * ASEG;

        // Phase B: stage fp16 windows as uint4 (16B, 2 positions per chunk).
        // base even -> global src 16B-aligned; LDS dst 16B-aligned.
        for (int idx = t; idx < ASEG * WCHK; idx += 256) {
            const int al = idx / WCHK;
            const int i = idx - al * WCHK;
            const int a = A0 + al;
            const int base = 256 - (int)qrow[a];          // lane-varying -> v-load
            const u32* gsrc = (const u32*)(fil2h + a * FSH + FOFFH + 4 * base);
            const uint4 vv = *(const uint4*)(gsrc + 4 * i);
            *(uint4*)(win32 + al * WU32 + 4 * i) = vv;
        }
        __syncthreads();

        // Phase C: q = p - base in [~2, 26); j = trunc(q); u32[2j..2j+3] =
        // both taps x 4 batches (16B) -> two adjacent uint2 LDS reads.
        #pragma unroll 4
        for (int al = 0; al < ASEG; ++al) {
            const float ss = SCT.sc[A0 + al][0];          // wave-uniform -> s_load
            const float cc = SCT.sc[A0 + al][1];
            const float qb = qrow[A0 + al];               // wave-uniform -> s_load
            const float q = fmaf(xf, ss, fmaf(yf, cc, qb));
            const int j = (int)q;
            const float fr = FRACT(q);
            const float omf = 1.f - fr;
            const u32* wr = win32 + al * WU32 + 2 * j;    // 8B-aligned
            const uint2 t0 = *(const uint2*)(wr);         // pos j:   b0b1, b2b3
            const uint2 t1 = *(const uint2*)(wr + 2);     // pos j+1: b0b1, b2b3
            const float2 f00 = h2f2(t0.x);                // (b0, b1) @ j
            const float2 f01 = h2f2(t0.y);                // (b2, b3) @ j
            const float2 f10 = h2f2(t1.x);                // (b0, b1) @ j+1
            const float2 f11 = h2f2(t1.y);                // (b2, b3) @ j+1
            acc0 = fmaf(omf, f00.x, fmaf(fr, f10.x, acc0));
            acc1 = fmaf(omf, f00.y, fmaf(fr, f10.y, acc1));
            acc2 = fmaf(omf, f01.x, fmaf(fr, f11.x, acc2));
            acc3 = fmaf(omf, f01.y, fmaf(fr, f11.y, acc3));
        }
        if (seg < 2) __syncthreads();    // protect win before restage (uniform)
    }

    const float scale = (float)(M_PI / (2.0 * NA));
    o0[0]                 = m ? acc0 * scale : 0.f;
    o0[(size_t)P * P]     = m ? acc1 * scale : 0.f;
    o0[(size_t)2 * P * P] = m ? acc2 * scale : 0.f;
    o0[(size_t)3 * P * P] = m ? acc3 * scale : 0.f;
}

// ---------------------------------------------------------------------------
extern "C" void kernel_launch(void* const* d_in, const int* in_sizes, int n_in,
                              void* d_out, int out_size, void* d_ws, size_t ws_size,
                              hipStream_t stream) {
    const float* sino = (const float*)d_in[0];
    float* out = (float*)d_out;
    float* ws = (float*)d_ws;

    float* qbt = ws;                          // 1024 tiles * 180 floats
    _Float16* fil2h = (_Float16*)(ws + NTILES * NA + GUARD);  // 180*2176 halves, 16B aligned

    ir_filter<<<NA, 512, 0, stream>>>(sino, fil2h, qbt);

    dim3 gridB(P / TS, P / TS, 1);            // 1024 blocks, 4 batches in-block
    ir_backproject<<<gridB, 256, 0, stream>>>(fil2h, qbt, out);
}